// Round 1
// baseline (192.662 us; speedup 1.0000x reference)
//
#include <hip/hip_runtime.h>

#define N_NODES 100000
#define N_EDGES 640000
#define HIDDEN 128

// ---------------------------------------------------------------------------
// Phase 1: edge scatter for layer 1.  agg1[dst][0:4] += x[src][0:4] * w_e
// ---------------------------------------------------------------------------
__global__ void scatter1_kernel(const int* __restrict__ ei,
                                const float* __restrict__ ea,
                                const float* __restrict__ x,
                                float* __restrict__ agg) {
    int e = blockIdx.x * blockDim.x + threadIdx.x;
    if (e >= N_EDGES) return;
    int src = ei[e];
    int dst = ei[N_EDGES + e];
    float w = ea[e];
    float4 xv = reinterpret_cast<const float4*>(x)[src];
    atomicAdd(&agg[dst * 4 + 0], xv.x * w);
    atomicAdd(&agg[dst * 4 + 1], xv.y * w);
    atomicAdd(&agg[dst * 4 + 2], xv.z * w);
    atomicAdd(&agg[dst * 4 + 3], xv.w * w);
}

// ---------------------------------------------------------------------------
// Phase 2: per-node fused MLP.
//   h[j]    = relu(b1[j] + sum_k agg[k]*W1_rel[k][j] + sum_k x[k]*W1_root[k][j])
//   s_rel   = sum_j h[j]*W2_rel[j]      (feeds the layer-2 scatter)
//   out[n]  = sum_j h[j]*W2_root[j] + b2   (the root term of layer 2)
// h never touches global memory.
// ---------------------------------------------------------------------------
__global__ void node_kernel(const float* __restrict__ x,
                            const float* __restrict__ agg,
                            const float* __restrict__ W1_rel,
                            const float* __restrict__ b1,
                            const float* __restrict__ W1_root,
                            const float* __restrict__ W2_rel,
                            const float* __restrict__ b2,
                            const float* __restrict__ W2_root,
                            float* __restrict__ s_rel,
                            float* __restrict__ out) {
    __shared__ float sW1r[4 * HIDDEN];
    __shared__ float sW1o[4 * HIDDEN];
    __shared__ float sb1[HIDDEN];
    __shared__ float sW2r[HIDDEN];
    __shared__ float sW2o[HIDDEN];

    for (int i = threadIdx.x; i < 4 * HIDDEN; i += blockDim.x) {
        sW1r[i] = W1_rel[i];
        sW1o[i] = W1_root[i];
    }
    for (int i = threadIdx.x; i < HIDDEN; i += blockDim.x) {
        sb1[i]  = b1[i];
        sW2r[i] = W2_rel[i];
        sW2o[i] = W2_root[i];
    }
    __syncthreads();

    int n = blockIdx.x * blockDim.x + threadIdx.x;
    if (n >= N_NODES) return;

    float4 xv = reinterpret_cast<const float4*>(x)[n];
    float4 av = reinterpret_cast<const float4*>(agg)[n];

    float srel = 0.f, sroot = 0.f;
#pragma unroll 4
    for (int j = 0; j < HIDDEN; ++j) {
        float pre = sb1[j]
                  + av.x * sW1r[0 * HIDDEN + j]
                  + av.y * sW1r[1 * HIDDEN + j]
                  + av.z * sW1r[2 * HIDDEN + j]
                  + av.w * sW1r[3 * HIDDEN + j]
                  + xv.x * sW1o[0 * HIDDEN + j]
                  + xv.y * sW1o[1 * HIDDEN + j]
                  + xv.z * sW1o[2 * HIDDEN + j]
                  + xv.w * sW1o[3 * HIDDEN + j];
        float h = fmaxf(pre, 0.f);
        srel  += h * sW2r[j];
        sroot += h * sW2o[j];
    }
    s_rel[n] = srel;
    out[n]   = sroot + b2[0];
}

// ---------------------------------------------------------------------------
// Phase 3: scalar edge scatter for layer 2.  out[dst] += s_rel[src] * w_e
// ---------------------------------------------------------------------------
__global__ void scatter2_kernel(const int* __restrict__ ei,
                                const float* __restrict__ ea,
                                const float* __restrict__ s_rel,
                                float* __restrict__ out) {
    int e = blockIdx.x * blockDim.x + threadIdx.x;
    if (e >= N_EDGES) return;
    int src = ei[e];
    int dst = ei[N_EDGES + e];
    atomicAdd(&out[dst], s_rel[src] * ea[e]);
}

extern "C" void kernel_launch(void* const* d_in, const int* in_sizes, int n_in,
                              void* d_out, int out_size, void* d_ws, size_t ws_size,
                              hipStream_t stream) {
    const float* x       = (const float*)d_in[0];
    const int*   ei      = (const int*)  d_in[1];
    const float* ea      = (const float*)d_in[2];
    const float* W1_rel  = (const float*)d_in[3];
    const float* b1      = (const float*)d_in[4];
    const float* W1_root = (const float*)d_in[5];
    const float* W2_rel  = (const float*)d_in[6];
    const float* b2      = (const float*)d_in[7];
    const float* W2_root = (const float*)d_in[8];
    float* out = (float*)d_out;

    // Workspace layout: agg1 [N*4 floats] | s_rel [N floats]
    float* agg   = (float*)d_ws;
    float* s_rel = agg + (size_t)N_NODES * 4;

    hipMemsetAsync(agg, 0, (size_t)N_NODES * 4 * sizeof(float), stream);

    dim3 blk(256);
    dim3 grdE((N_EDGES + 255) / 256);
    dim3 grdN((N_NODES + 255) / 256);

    scatter1_kernel<<<grdE, blk, 0, stream>>>(ei, ea, x, agg);
    node_kernel<<<grdN, blk, 0, stream>>>(x, agg, W1_rel, b1, W1_root,
                                          W2_rel, b2, W2_root, s_rel, out);
    scatter2_kernel<<<grdE, blk, 0, stream>>>(ei, ea, s_rel, out);
}